// Round 1
// baseline (590.852 us; speedup 1.0000x reference)
//
#include <hip/hip_runtime.h>
#include <math.h>

#define C_   128
#define T_   64
#define V_   25
#define TV   1600       // T_*V_
#define CTV  204800     // C_*TV
#define VP   28         // padded row stride (floats), 112 B = 16B-aligned
#define EPS  1e-5f

// Transpose conv weights so the per-c load in the main kernel is coalesced.
__global__ __launch_bounds__(256) void prep_transpose(
    const float* __restrict__ W1, const float* __restrict__ W2,
    float* __restrict__ W1T, float* __restrict__ W2T) {
  int i = blockIdx.x * 256 + threadIdx.x;
  if (i < 256 * 128) { int o = i >> 7, c = i & 127; W1T[c * 256 + o] = W1[i]; }
  if (i < 128 * 128) { int o = i >> 7, c = i & 127; W2T[c * 128 + o] = W2[i]; }
}

template <bool TW>
__global__ __launch_bounds__(256, 3) void fused_kernel(
    const float* __restrict__ x,
    const float* __restrict__ bn0g, const float* __restrict__ bn0b,
    const float* __restrict__ bn0m, const float* __restrict__ bn0v,
    const float* __restrict__ W1,   const float* __restrict__ b1,
    const float* __restrict__ bn1g, const float* __restrict__ bn1b,
    const float* __restrict__ bn1m, const float* __restrict__ bn1v,
    const float* __restrict__ bn2g, const float* __restrict__ bn2b,
    const float* __restrict__ bn2m, const float* __restrict__ bn2v,
    const float* __restrict__ topo, const float* __restrict__ spat,
    const float* __restrict__ W2,   const float* __restrict__ b2,
    const float* __restrict__ W1T,  const float* __restrict__ W2T,
    float* __restrict__ out) {
  // sA: h (BN0(x)) during conv1, then y during/after spatial
  // sB: z1;  sC: z2, then conv2 result
  __shared__ float sA[C_ * VP];
  __shared__ float sB[C_ * VP];
  __shared__ float sC[C_ * VP];

  const int bt = blockIdx.x;          // 0..8191
  const int b  = bt >> 6;
  const int t  = bt & 63;
  const float* xs = x + (size_t)b * CTV + t * V_;
  float*       os = out + (size_t)b * CTV + t * V_;
  const int tid = threadIdx.x;

  // ---------- phase 0: load x slice, apply BN0 -> sA ----------
  {
    const int v = tid & 31, r0 = tid >> 5;   // 8 rows per pass, 32 lanes/row
    if (v < V_) {
      for (int p = 0; p < 16; ++p) {
        int c = p * 8 + r0;
        float inv = bn0g[c] * rsqrtf(bn0v[c] + EPS);
        float add = fmaf(-bn0m[c], inv, bn0b[c]);
        sA[c * VP + v] = fmaf(xs[c * TV + v], inv, add);
      }
    }
  }
  __syncthreads();

  // ---------- phase 1: conv1 (o = tid), GELU exact, BN1/BN2 -> sB/sC ----------
  {
    float acc[25];
    float bb = b1[tid];
    #pragma unroll
    for (int v = 0; v < 25; ++v) acc[v] = bb;

    #pragma unroll 4
    for (int c = 0; c < 128; ++c) {
      float w = TW ? W1T[c * 256 + tid] : W1[tid * 128 + c];
      const float* hr = &sA[c * VP];      // wave-broadcast ds_read_b128s
      #pragma unroll
      for (int v = 0; v < 25; ++v) acc[v] = fmaf(w, hr[v], acc[v]);
    }

    const int oz = tid & 127;
    float inv, add;
    if (tid < 128) {
      inv = bn1g[oz] * rsqrtf(bn1v[oz] + EPS);
      add = fmaf(-bn1m[oz], inv, bn1b[oz]);
    } else {
      inv = bn2g[oz] * rsqrtf(bn2v[oz] + EPS);
      add = fmaf(-bn2m[oz], inv, bn2b[oz]);
    }
    float* dst = (tid < 128 ? sB : sC) + oz * VP;
    #pragma unroll
    for (int v = 0; v < 25; ++v) {
      float a = acc[v];
      float g = 0.5f * a * (1.0f + erff(a * 0.70710678118654752440f));
      dst[v] = fmaf(g, inv, add);
    }
  }
  __syncthreads();

  // ---------- phase 2: spatial mixing, y -> sA ----------
  {
    const int c2 = tid & 127;
    const int hh = c2 >> 5;               // head = c/32
    const float* At  = topo + hh * 625;
    const float* Wsp = spat + hh * 625;
    const float* z1r = &sB[c2 * VP];
    const float* z2r = &sC[c2 * VP];
    float z1v[25], z2v[25];
    #pragma unroll
    for (int v = 0; v < 25; ++v) { z1v[v] = z1r[v]; z2v[v] = z2r[v]; }

    const int u0 = (tid >> 7) ? 13 : 0;
    const int u1 = (tid >> 7) ? 25 : 13;
    for (int u = u0; u < u1; ++u) {
      float ay = 0.f, aa = 0.f;
      #pragma unroll
      for (int v = 0; v < 25; ++v) {
        ay = fmaf(At[u * 25 + v],  z1v[v], ay);
        aa = fmaf(Wsp[u * 25 + v], z2v[v], aa);
      }
      // y = y1 + z1 * attn   (z1r[u] from LDS: avoids runtime-indexed regs)
      sA[c2 * VP + u] = fmaf(z1r[u], aa, ay);
    }
  }
  __syncthreads();

  // ---------- phase 3: conv2 (o = tid&127, v-halves 0..11 / 12..24) -> sC ----------
  {
    const int o = tid & 127;
    const float bb = b2[o];
    if (tid < 128) {
      float a2[12];
      #pragma unroll
      for (int j = 0; j < 12; ++j) a2[j] = bb;
      #pragma unroll 4
      for (int c = 0; c < 128; ++c) {
        float w = TW ? W2T[c * 128 + o] : W2[o * 128 + c];
        const float* yr = &sA[c * VP];    // broadcast
        #pragma unroll
        for (int j = 0; j < 12; ++j) a2[j] = fmaf(w, yr[j], a2[j]);
      }
      #pragma unroll
      for (int j = 0; j < 12; ++j) sC[o * VP + j] = a2[j];
    } else {
      float a2[13];
      #pragma unroll
      for (int j = 0; j < 13; ++j) a2[j] = bb;
      #pragma unroll 4
      for (int c = 0; c < 128; ++c) {
        float w = TW ? W2T[c * 128 + o] : W2[o * 128 + c];
        const float* yr = &sA[c * VP + 12];
        #pragma unroll
        for (int j = 0; j < 13; ++j) a2[j] = fmaf(w, yr[j], a2[j]);
      }
      #pragma unroll
      for (int j = 0; j < 13; ++j) sC[o * VP + 12 + j] = a2[j];
    }
  }
  __syncthreads();

  // ---------- phase 4: residual + ReLU, coalesced store ----------
  {
    const int v = tid & 31, r0 = tid >> 5;
    if (v < V_) {
      for (int p = 0; p < 16; ++p) {
        int c = p * 8 + r0;
        float val = sC[c * VP + v] + xs[c * TV + v];
        os[c * TV + v] = fmaxf(val, 0.0f);
      }
    }
  }
}

extern "C" void kernel_launch(void* const* d_in, const int* in_sizes, int n_in,
                              void* d_out, int out_size, void* d_ws, size_t ws_size,
                              hipStream_t stream) {
  const float* x    = (const float*)d_in[0];
  const float* bn0g = (const float*)d_in[1];
  const float* bn0b = (const float*)d_in[2];
  const float* bn0m = (const float*)d_in[3];
  const float* bn0v = (const float*)d_in[4];
  const float* W1   = (const float*)d_in[5];
  const float* b1   = (const float*)d_in[6];
  const float* bn1g = (const float*)d_in[7];
  const float* bn1b = (const float*)d_in[8];
  const float* bn1m = (const float*)d_in[9];
  const float* bn1v = (const float*)d_in[10];
  const float* bn2g = (const float*)d_in[11];
  const float* bn2b = (const float*)d_in[12];
  const float* bn2m = (const float*)d_in[13];
  const float* bn2v = (const float*)d_in[14];
  const float* topo = (const float*)d_in[15];
  const float* spat = (const float*)d_in[16];
  const float* W2   = (const float*)d_in[17];
  const float* b2   = (const float*)d_in[18];
  float* out = (float*)d_out;

  const size_t need = (size_t)(256 * 128 + 128 * 128) * sizeof(float);
  if (ws_size >= need) {
    float* W1T = (float*)d_ws;
    float* W2T = W1T + 256 * 128;
    prep_transpose<<<128, 256, 0, stream>>>(W1, W2, W1T, W2T);
    fused_kernel<true><<<8192, 256, 0, stream>>>(
        x, bn0g, bn0b, bn0m, bn0v, W1, b1, bn1g, bn1b, bn1m, bn1v,
        bn2g, bn2b, bn2m, bn2v, topo, spat, W2, b2, W1T, W2T, out);
  } else {
    fused_kernel<false><<<8192, 256, 0, stream>>>(
        x, bn0g, bn0b, bn0m, bn0v, W1, b1, bn1g, bn1b, bn1m, bn1v,
        bn2g, bn2b, bn2m, bn2v, topo, spat, W2, b2, W1, W2, out);
  }
}